// Round 10
// baseline (187.608 us; speedup 1.0000x reference)
//
#include <hip/hip_runtime.h>
#include <hip/hip_bf16.h>

// B=4, S=2048, D=512. fp32 in/out, bf16 MFMA internals.
// E = 1 + F with F = expm1(scale*s) lower-tri, 0 above. Then
//   out  = F @ vp' + T,  vp' = vp/Z,  T[d] = sum_k vp'[k,d],  Z[k] = 2048+colsum(F)
// Pipeline:
//   cvt6: q,k,v,W* fp32 -> bf16 (one launch)
//   proj3: qp,kp,vpT (64x128 tiles, 1536 blocks, 3 blocks/CU)
//   scoresF: lower-tri F tiles (64x128, 1088 blocks) + non-atomic partial
//            colsums ZP[b][rowblk][k]
//   zfin:  rsZ = 1/(2048 + sum_i ZP)
//   scaleT: vpT *= rsZ (per k), Tv = rowsum (fp32)
//   outF: F @ vpT'^T + Tv -> fp32 d_out (64x128, K-trunc, triple-buffered)
// Cores: BK=64, global_load_lds width-16, XOR(row&7) swizzle (0 bank conflicts),
// cross-barrier prefetch with raw s_barrier + fine vmcnt.

#define S_LEN 2048
#define D_DIM 512
#define SCALE_F 0.044194173824159216f  // 1/sqrt(512)

typedef __attribute__((ext_vector_type(8))) short s8v;   // 8 bf16 = 4 VGPRs
typedef __attribute__((ext_vector_type(4))) short s4v;   // 4 bf16 = 8 B
typedef __attribute__((ext_vector_type(4))) float f4v;   // MFMA accumulator

enum { EPI_BIAS = 0, EPI_BIAS_T = 1, EPI_SCORES = 2 };

#define SBAR()    asm volatile("s_barrier" ::: "memory")
#define WAITV(n)  asm volatile("s_waitcnt vmcnt(" #n ")" ::: "memory")

__device__ __forceinline__ short f2bf_s(float f) {
  union { __hip_bfloat16 b; short s; } u; u.b = __float2bfloat16(f); return u.s;
}
__device__ __forceinline__ float bf2f_s(short h) {
  union { short s; __hip_bfloat16 b; } u; u.s = h; return __bfloat162float(u.b);
}

__device__ __forceinline__ void glds16(const short* g, short* l) {
  __builtin_amdgcn_global_load_lds((const __attribute__((address_space(1))) void*)g,
                                   (__attribute__((address_space(3))) void*)l, 16, 0, 0);
}

// Core NT GEMM, (NI*32) x 128 tile at (m0,n0), BK=64, double-buffered LDS.
// NI = 16-row groups per wave (2 -> 64-row tile, 4 -> 128-row tile).
// SMEM: buf c at c*(NI*2048+8192); As = +0, Bs = +NI*2048. shorts.
template <int EPI, int NI>
__device__ __forceinline__ void gemm_core(
    const short* __restrict__ A, const short* __restrict__ B,
    short* __restrict__ C, const float* __restrict__ bias,
    short* SMEM, int N, int K, size_t sCz, int m0, int n0, int bz,
    float* __restrict__ ZP)
{
  const int tid  = threadIdx.x;
  const int w    = tid >> 6;
  const int lane = tid & 63;
  const int quad = lane >> 4;
  const int l16  = lane & 15;
  const int wm   = (w >> 1) * (NI * 16);
  const int wn   = (w & 1) * 64;

  const int strow = tid >> 3;                         // 0..31
  const int gl = ((tid & 7) ^ (strow & 7)) * 8;       // XOR column-group swizzle

  f4v acc[NI][4];
#pragma unroll
  for (int i = 0; i < NI; ++i)
#pragma unroll
    for (int j = 0; j < 4; ++j)
#pragma unroll
      for (int r = 0; r < 4; ++r) acc[i][j][r] = 0.0f;

  const short* Ag = A + (size_t)(m0 + strow) * K + gl;
  const short* Bg = B + (size_t)(n0 + strow) * K + gl;
  const size_t pstr = (size_t)32 * K;
  const int t8 = tid * 8;
  const int swq = l16 & 7;
  constexpr int ABUF = NI * 2048;
  constexpr int BUFS = ABUF + 8192;

  const int niter = K >> 6;

#pragma unroll
  for (int p = 0; p < NI; ++p) glds16(Ag + p * pstr, SMEM + t8 + p * 2048);
#pragma unroll
  for (int p = 0; p < 4; ++p) glds16(Bg + p * pstr, SMEM + ABUF + t8 + p * 2048);

  for (int i = 0; i < niter; ++i) {
    const int c = i & 1;
    if (i + 1 < niter) {
      const int k1 = (i + 1) << 6;
      short* dst = SMEM + (1 - c) * BUFS + t8;
#pragma unroll
      for (int p = 0; p < NI; ++p) glds16(Ag + k1 + p * pstr, dst + p * 2048);
#pragma unroll
      for (int p = 0; p < 4; ++p) glds16(Bg + k1 + p * pstr, dst + ABUF + p * 2048);
      if constexpr (NI == 4) { WAITV(8); } else { WAITV(6); }
    } else {
      WAITV(0);
    }
    SBAR();

    const short* As = SMEM + c * BUFS;
    const short* Bs = As + ABUF;
#pragma unroll
    for (int kk = 0; kk < 2; ++kk) {
      s8v af[NI], bf[4];
#pragma unroll
      for (int ii = 0; ii < NI; ++ii)
        af[ii] = *(const s8v*)&As[(wm + ii * 16 + l16) * 64 + (((kk * 4 + quad) ^ swq) * 8)];
#pragma unroll
      for (int j = 0; j < 4; ++j)
        bf[j] = *(const s8v*)&Bs[(wn + j * 16 + l16) * 64 + (((kk * 4 + quad) ^ swq) * 8)];
#pragma unroll
      for (int ii = 0; ii < NI; ++ii)
#pragma unroll
        for (int j = 0; j < 4; ++j)
          acc[ii][j] = __builtin_amdgcn_mfma_f32_16x16x32_bf16(af[ii], bf[j], acc[ii][j], 0, 0, 0);
    }
    SBAR();
  }

  // ---- epilogue ----
  float bv[4];
  if (EPI == EPI_BIAS || EPI == EPI_BIAS_T) {
#pragma unroll
    for (int j = 0; j < 4; ++j) bv[j] = bias[n0 + wn + j * 16 + l16];
  }

  if (EPI == EPI_BIAS_T) {
#pragma unroll
    for (int i = 0; i < NI; ++i) {
#pragma unroll
      for (int j = 0; j < 4; ++j) {
        const int gn  = n0 + wn + j * 16 + l16;
        const int gmb = m0 + wm + i * 16 + quad * 4;
        const int bb = gmb >> 11, ssb = gmb & (S_LEN - 1);
        s4v o;
#pragma unroll
        for (int r = 0; r < 4; ++r) o[r] = f2bf_s(acc[i][j][r] + bv[j]);
        *(s4v*)&C[((size_t)bb * D_DIM + gn) * S_LEN + ssb] = o;
      }
    }
    return;
  }

  // EPI_BIAS / EPI_SCORES: LDS transpose -> coalesced 16B row stores.
  short* TB = SMEM;                 // 4 waves x 2176 shorts (32 rows x stride 68)
  const int wbase = w * 2176;
  float csum[4] = {0.f, 0.f, 0.f, 0.f};

#pragma unroll
  for (int ph = 0; ph < NI / 2; ++ph) {
    __syncthreads();
#pragma unroll
    for (int ii = 0; ii < 2; ++ii) {
      const int i = ph * 2 + ii;
#pragma unroll
      for (int j = 0; j < 4; ++j) {
        const int gn = n0 + wn + j * 16 + l16;
#pragma unroll
        for (int r = 0; r < 4; ++r) {
          short o;
          if (EPI == EPI_SCORES) {
            const int gm = m0 + wm + i * 16 + quad * 4 + r;
            const float f = (gm >= gn) ? (__expf(acc[i][j][r] * SCALE_F) - 1.0f) : 0.0f;
            csum[j] += f;
            o = f2bf_s(f);
          } else {
            o = f2bf_s(acc[i][j][r] + bv[j]);
          }
          TB[wbase + (ii * 16 + quad * 4 + r) * 68 + j * 16 + l16] = o;
        }
      }
    }
    __syncthreads();
#pragma unroll
    for (int p = 0; p < 4; ++p) {
      const int row = p * 8 + (lane >> 3);   // 0..31
      const int cg  = lane & 7;
      const s8v vv = *(const s8v*)&TB[wbase + row * 68 + cg * 8];
      const int gm = m0 + wm + ph * 32 + row;
      const int gn = n0 + wn + cg * 8;
      *(s8v*)&C[sCz + (size_t)gm * N + gn] = vv;
    }
  }

  if (EPI == EPI_SCORES) {
    // per-block partial column sums -> ZP[bz][m0>>6][n0..n0+128), non-atomic.
    float* LZ = (float*)(SMEM + 20480);   // 256 floats, beyond TB region
#pragma unroll
    for (int j = 0; j < 4; ++j) {
      float cs = csum[j];
      cs += __shfl_xor(cs, 16, 64);
      cs += __shfl_xor(cs, 32, 64);
      if (quad == 0) LZ[(w >> 1) * 128 + wn + j * 16 + l16] = cs;
    }
    __syncthreads();
    if (tid < 128)
      ZP[(((bz << 5) + (m0 >> 6)) << 11) + n0 + tid] = LZ[tid] + LZ[128 + tid];
  }
}

// scores-F kernel: 64x128 tiles, compact triangular grid x in [0,272), z=batch.
__global__ __launch_bounds__(256, 3) void gemm_scoresF(
    const short* __restrict__ A, const short* __restrict__ B, short* __restrict__ C,
    float* __restrict__ ZP)
{
  __shared__ __align__(16) short SMEM[24576];   // 48 KB: 2 x (A 64x64 + B 128x64)
  const int bz = blockIdx.z;
  const int t = blockIdx.x;
  int j = (int)((sqrtf(4.0f * t + 1.0f) - 1.0f) * 0.5f);
  while ((j + 1) * (j + 2) <= t) ++j;
  while (j * (j + 1) > t) --j;
  const int off = t - j * (j + 1);
  const int ti = (off < j + 1) ? 2 * j : 2 * j + 1;
  const int tc = (off < j + 1) ? off : off - (j + 1);
  gemm_core<EPI_SCORES, 2>(A + (size_t)bz * S_LEN * D_DIM, B + (size_t)bz * S_LEN * D_DIM,
                           C, nullptr, SMEM, S_LEN, D_DIM,
                           (size_t)bz * S_LEN * S_LEN, ti * 64, tc * 128, bz, ZP);
}

// three projections: 64x128 tiles, z=0 -> qp, z=1 -> kp, z=2 -> vpT (transposed)
__global__ __launch_bounds__(256, 3) void proj3(
    const short* __restrict__ a0, const short* __restrict__ a1, const short* __restrict__ a2,
    const short* __restrict__ b0, const short* __restrict__ b1, const short* __restrict__ b2,
    short* __restrict__ c0, short* __restrict__ c1, short* __restrict__ c2,
    const float* __restrict__ x0, const float* __restrict__ x1, const float* __restrict__ x2)
{
  __shared__ __align__(16) short SMEM[24576];
  const int z = blockIdx.z;
  const short* A = (z == 0) ? a0 : (z == 1) ? a1 : a2;
  const short* B = (z == 0) ? b0 : (z == 1) ? b1 : b2;
  short*       C = (z == 0) ? c0 : (z == 1) ? c1 : c2;
  const float* bias = (z == 0) ? x0 : (z == 1) ? x1 : x2;
  if (z == 2)
    gemm_core<EPI_BIAS_T, 2>(A, B, C, bias, SMEM, D_DIM, D_DIM, 0,
                             blockIdx.y * 64, blockIdx.x * 128, 0, nullptr);
  else
    gemm_core<EPI_BIAS, 2>(A, B, C, bias, SMEM, D_DIM, D_DIM, 0,
                           blockIdx.y * 64, blockIdx.x * 128, 0, nullptr);
}

// out = F @ vpT'^T + T, 64x128 tiles, K truncated at m0+64, triple-buffered.
// SMEM: buf c at c*12288; As=+0 (64x64), Bs=+4096 (128x64).
__global__ __launch_bounds__(256, 2) void gemm_outF(
    const short* __restrict__ F, const short* __restrict__ vpT,
    const float* __restrict__ Tv, float* __restrict__ out)
{
  __shared__ __align__(16) short SMEM[36864];   // 72 KB

  const int tid  = threadIdx.x;
  const int bz   = blockIdx.z;
  const int m0   = (31 - blockIdx.y) * 64;      // longest blocks dispatch first
  const int n0   = blockIdx.x * 128;

  const short* A = F   + (size_t)bz * S_LEN * S_LEN;
  const short* B = vpT + (size_t)bz * D_DIM * S_LEN;

  const int w    = tid >> 6;
  const int lane = tid & 63;
  const int quad = lane >> 4;
  const int l16  = lane & 15;
  const int wm   = (w >> 1) * 32;
  const int wn   = (w & 1) * 64;

  const int strow = tid >> 3;
  const int gl = ((tid & 7) ^ (strow & 7)) * 8;

  f4v acc[2][4];
#pragma unroll
  for (int i = 0; i < 2; ++i)
#pragma unroll
    for (int j = 0; j < 4; ++j)
#pragma unroll
      for (int r = 0; r < 4; ++r) acc[i][j][r] = 0.0f;

  const short* Ag = A + (size_t)(m0 + strow) * S_LEN + gl;
  const short* Bg = B + (size_t)(n0 + strow) * S_LEN + gl;
  const size_t pstr = (size_t)32 * S_LEN;
  const int t8 = tid * 8;
  const int swq = l16 & 7;

  const int niter = (m0 >> 6) + 1;   // K runs 0 .. m0+64

#pragma unroll
  for (int pre = 0; pre < 2; ++pre) {
    short* dst = SMEM + pre * 12288 + t8;
    const int k0 = pre << 6;
#pragma unroll
    for (int p = 0; p < 2; ++p) glds16(Ag + k0 + p * pstr, dst + p * 2048);
#pragma unroll
    for (int p = 0; p < 4; ++p) glds16(Bg + k0 + p * pstr, dst + 4096 + p * 2048);
  }

  int cbuf = 0, nbuf = 2;
  for (int i = 0; i < niter; ++i) {
    if (i + 2 < niter) {
      const int k2 = (i + 2) << 6;
      short* dst = SMEM + nbuf * 12288 + t8;
#pragma unroll
      for (int p = 0; p < 2; ++p) glds16(Ag + k2 + p * pstr, dst + p * 2048);
#pragma unroll
      for (int p = 0; p < 4; ++p) glds16(Bg + k2 + p * pstr, dst + 4096 + p * 2048);
      nbuf = (nbuf == 2) ? 0 : nbuf + 1;
      WAITV(12);
    } else if (i + 1 < niter) {
      WAITV(6);
    } else {
      WAITV(0);
    }
    SBAR();

    const short* As = SMEM + cbuf * 12288;
    const short* Bs = As + 4096;
    cbuf = (cbuf == 2) ? 0 : cbuf + 1;
#pragma unroll
    for (int kk = 0; kk < 2; ++kk) {
      s8v af[2], bf[4];
#pragma unroll
      for (int ii = 0; ii < 2; ++ii)
        af[ii] = *(const s8v*)&As[(wm + ii * 16 + l16) * 64 + (((kk * 4 + quad) ^ swq) * 8)];
#pragma unroll
      for (int j = 0; j < 4; ++j)
        bf[j] = *(const s8v*)&Bs[(wn + j * 16 + l16) * 64 + (((kk * 4 + quad) ^ swq) * 8)];
#pragma unroll
      for (int ii = 0; ii < 2; ++ii)
#pragma unroll
        for (int j = 0; j < 4; ++j)
          acc[ii][j] = __builtin_amdgcn_mfma_f32_16x16x32_bf16(af[ii], bf[j], acc[ii][j], 0, 0, 0);
    }
    SBAR();
  }

  float* Cf = out + (size_t)bz * S_LEN * D_DIM;
#pragma unroll
  for (int i = 0; i < 2; ++i) {
#pragma unroll
    for (int j = 0; j < 4; ++j) {
      const int gn = n0 + wn + j * 16 + l16;
      const float tvn = Tv[(bz << 9) + gn];
#pragma unroll
      for (int r = 0; r < 4; ++r) {
        const int gm = m0 + wm + i * 16 + quad * 4 + r;
        Cf[(size_t)gm * D_DIM + gn] = acc[i][j][r] + tvn;
      }
    }
  }
}

// one launch for all fp32->bf16 conversions: x<2048 -> q/k/v slab y, else weights y
__global__ __launch_bounds__(256) void cvt6(
    const float* __restrict__ q, const float* __restrict__ k, const float* __restrict__ v,
    const float* __restrict__ wq, const float* __restrict__ wk, const float* __restrict__ wv,
    short* __restrict__ dstBig, short* __restrict__ dstW)
{
  const int y = blockIdx.y;
  const float* s;
  short* d;
  int i;
  if (blockIdx.x < 2048) {
    s = (y == 0) ? q : (y == 1) ? k : v;
    d = dstBig + (size_t)y * 4194304;
    i = (blockIdx.x * 256 + threadIdx.x) * 8;
  } else {
    s = (y == 0) ? wq : (y == 1) ? wk : wv;
    d = dstW + (size_t)y * 262144;
    i = ((blockIdx.x - 2048) * 256 + threadIdx.x) * 8;
  }
  const float4 f0 = *(const float4*)(s + i);
  const float4 f1 = *(const float4*)(s + i + 4);
  s8v o;
  o[0] = f2bf_s(f0.x); o[1] = f2bf_s(f0.y); o[2] = f2bf_s(f0.z); o[3] = f2bf_s(f0.w);
  o[4] = f2bf_s(f1.x); o[5] = f2bf_s(f1.y); o[6] = f2bf_s(f1.z); o[7] = f2bf_s(f1.w);
  *(s8v*)(d + i) = o;
}

// rsZ[b][k] = 1/(2048 + sum_{i=2*(k>>7)}^{31} ZP[b][i][k])
__global__ __launch_bounds__(256) void zfin(
    const float* __restrict__ ZP, float* __restrict__ rsZ)
{
  const int idx = blockIdx.x * 256 + threadIdx.x;   // < 8192
  const int b = idx >> 11, kk = idx & (S_LEN - 1);
  float s = 2048.0f;
  for (int i = 2 * (kk >> 7); i < 32; ++i)
    s += ZP[(((b << 5) + i) << 11) + kk];
  rsZ[idx] = 1.0f / s;
}

// block per (b,d): vpT[b][d][k] *= rsZ[b][k]; Tv[b,d] = sum_k (fp32)
__global__ __launch_bounds__(256) void scale_vpt_T(
    short* __restrict__ vpT, const float* __restrict__ rsZ, float* __restrict__ Tv)
{
  __shared__ float red[4];
  const int b = blockIdx.y, d = blockIdx.x, tid = threadIdx.x;
  const size_t rowbase = ((size_t)(b * D_DIM + d)) * S_LEN;
  const float* rz = rsZ + (b << 11);
  const int k0 = tid * 8;

  const float4 z0 = *(const float4*)&rz[k0];
  const float4 z1 = *(const float4*)&rz[k0 + 4];
  s8v v = *(s8v*)&vpT[rowbase + k0];
  float s = 0.0f;
  float wv0 = bf2f_s(v[0]) * z0.x, wv1 = bf2f_s(v[1]) * z0.y;
  float wv2 = bf2f_s(v[2]) * z0.z, wv3 = bf2f_s(v[3]) * z0.w;
  float wv4 = bf2f_s(v[4]) * z1.x, wv5 = bf2f_s(v[5]) * z1.y;
  float wv6 = bf2f_s(v[6]) * z1.z, wv7 = bf2f_s(v[7]) * z1.w;
  s = ((wv0 + wv1) + (wv2 + wv3)) + ((wv4 + wv5) + (wv6 + wv7));
  v[0] = f2bf_s(wv0); v[1] = f2bf_s(wv1); v[2] = f2bf_s(wv2); v[3] = f2bf_s(wv3);
  v[4] = f2bf_s(wv4); v[5] = f2bf_s(wv5); v[6] = f2bf_s(wv6); v[7] = f2bf_s(wv7);
  *(s8v*)&vpT[rowbase + k0] = v;

#pragma unroll
  for (int off = 32; off >= 1; off >>= 1) s += __shfl_xor(s, off, 64);
  if ((tid & 63) == 0) red[tid >> 6] = s;
  __syncthreads();
  if (tid == 0) Tv[(b << 9) + d] = red[0] + red[1] + red[2] + red[3];
}

extern "C" void kernel_launch(void* const* d_in, const int* in_sizes, int n_in,
                              void* d_out, int out_size, void* d_ws, size_t ws_size,
                              hipStream_t stream) {
  const float* q   = (const float*)d_in[0];
  const float* k   = (const float*)d_in[1];
  const float* v   = (const float*)d_in[2];
  const float* WQw = (const float*)d_in[3];
  const float* WQb = (const float*)d_in[4];
  const float* WKw = (const float*)d_in[5];
  const float* WKb = (const float*)d_in[6];
  const float* WVw = (const float*)d_in[7];
  const float* WVb = (const float*)d_in[8];

  char* ws = (char*)d_ws;
  // F occupies [0,32M); bf16 input/weight copies alias its head (dead before F written)
  short* F   = (short*)(ws);                 // 32 MB  [4][2048][2048] (lower tiles only)
  short* qb  = (short*)(ws);                 //  8 MB  (qb,kb,vb contiguous)
  short* Wqb = (short*)(ws + 25165824);      // 3x 512 KB contiguous
  short* qp  = (short*)(ws + 33554432);      //  8 MB  [4][2048][512]
  short* kp  = (short*)(ws + 41943040);      //  8 MB
  short* vpT = (short*)(ws + 50331648);      //  8 MB  [4][512][2048]
  float* ZP  = (float*)(ws + 58720256);      //  1 MB  [4][32][2048] partial colsums
  float* rsZ = (float*)(ws + 59768832);      // 32 KB  [4][2048]
  float* Tv  = (float*)(ws + 59801600);      //  8 KB  [4][512]
  short* kb  = qb + 4194304;
  short* vb  = qb + 8388608;
  short* Wkb = Wqb + 262144;
  short* Wvb = Wqb + 524288;

  const dim3 blk(256);

  // all fp32 -> bf16 conversions, one launch
  cvt6<<<dim3(2176, 3), blk, 0, stream>>>(q, k, v, WQw, WKw, WVw, qb, Wqb);

  // projections: M=8192, N=512, K=512; 64x128 tiles -> 1536 blocks (3/CU)
  proj3<<<dim3(4, 128, 3), blk, 0, stream>>>(
      qb, kb, vb, Wqb, Wkb, Wvb, qp, kp, vpT, WQb, WKb, WVb);

  // F = expm1(scale*qp@kp^T) lower-tri 64x128 tiles + ZP partial colsums
  gemm_scoresF<<<dim3(272, 1, 4), blk, 0, stream>>>(qp, kp, F, ZP);

  // rsZ = 1/(2048 + colsum)
  zfin<<<dim3(32), blk, 0, stream>>>(ZP, rsZ);

  // vpT' = vpT * rsZ; Tv = rowsum(vpT')
  scale_vpt_T<<<dim3(512, 4), blk, 0, stream>>>(vpT, rsZ, Tv);

  // out = F @ vpT'^T + Tv: 64x128 tiles, K truncated at m0+64
  gemm_outF<<<dim3(4, 32, 4), blk, 0, stream>>>(F, vpT, Tv, (float*)d_out);
}

// Round 11
// 185.471 us; speedup vs baseline: 1.0115x; 1.0115x over previous
//
#include <hip/hip_runtime.h>
#include <hip/hip_bf16.h>

// B=4, S=2048, D=512. fp32 in/out, bf16 MFMA internals.
// E = 1 + F with F = expm1(scale*s) lower-tri, 0 above. Then
//   out  = F @ vp' + T,  vp' = vp/Z,  T[d] = sum_k vp'[k,d],  Z[k] = 2048+colsum(F)
// Pipeline:
//   cvt6: q,k,v,W* fp32 -> bf16 (one launch)
//   proj3: qp,kp,vpT (128x128 tiles, 768 blocks)   [64-tile variant regressed: r10]
//   scoresF: lower-tri F 128x128 tiles (136/batch) + non-atomic ZP partial colsums
//   zfin:  rsZ = 1/(2048 + sum_i ZP)
//   scaleT: vpT *= rsZ (per k), Tv = rowsum (fp32)
//   outF: F @ vpT'^T + Tv -> fp32 d_out (64x128, K-trunc, triple-buffered)
// Cores: BK=64, global_load_lds width-16, XOR(row&7) swizzle (0 bank conflicts),
// cross-barrier prefetch with raw s_barrier + fine vmcnt.

#define S_LEN 2048
#define D_DIM 512
#define SCALE_F 0.044194173824159216f  // 1/sqrt(512)

typedef __attribute__((ext_vector_type(8))) short s8v;   // 8 bf16 = 4 VGPRs
typedef __attribute__((ext_vector_type(4))) short s4v;   // 4 bf16 = 8 B
typedef __attribute__((ext_vector_type(4))) float f4v;   // MFMA accumulator

enum { EPI_BIAS = 0, EPI_BIAS_T = 1, EPI_SCORES = 2 };

#define SBAR()    asm volatile("s_barrier" ::: "memory")
#define WAITV(n)  asm volatile("s_waitcnt vmcnt(" #n ")" ::: "memory")

__device__ __forceinline__ short f2bf_s(float f) {
  union { __hip_bfloat16 b; short s; } u; u.b = __float2bfloat16(f); return u.s;
}
__device__ __forceinline__ float bf2f_s(short h) {
  union { short s; __hip_bfloat16 b; } u; u.s = h; return __bfloat162float(u.b);
}

__device__ __forceinline__ void glds16(const short* g, short* l) {
  __builtin_amdgcn_global_load_lds((const __attribute__((address_space(1))) void*)g,
                                   (__attribute__((address_space(3))) void*)l, 16, 0, 0);
}

// Core NT GEMM, 128x128 tile at (m0,n0), BK=64, double-buffered LDS.
// SMEM: buf c at c*16384; As = +0 (128x64), Bs = +8192 (128x64). shorts.
template <int EPI>
__device__ __forceinline__ void gemm_core(
    const short* __restrict__ A, const short* __restrict__ B,
    short* __restrict__ C, const float* __restrict__ bias,
    short* SMEM, int N, int K, size_t sCz, int m0, int n0, int bz,
    float* __restrict__ ZP)
{
  const int tid  = threadIdx.x;
  const int w    = tid >> 6;
  const int lane = tid & 63;
  const int quad = lane >> 4;
  const int l16  = lane & 15;
  const int wm   = (w >> 1) * 64;
  const int wn   = (w & 1) * 64;

  const int strow = tid >> 3;                         // 0..31
  const int gl = ((tid & 7) ^ (strow & 7)) * 8;       // XOR column-group swizzle

  f4v acc[4][4];
#pragma unroll
  for (int i = 0; i < 4; ++i)
#pragma unroll
    for (int j = 0; j < 4; ++j)
#pragma unroll
      for (int r = 0; r < 4; ++r) acc[i][j][r] = 0.0f;

  const short* Ag = A + (size_t)(m0 + strow) * K + gl;
  const short* Bg = B + (size_t)(n0 + strow) * K + gl;
  const size_t pstr = (size_t)32 * K;
  const int t8 = tid * 8;
  const int swq = l16 & 7;

  const int niter = K >> 6;

#pragma unroll
  for (int p = 0; p < 4; ++p) glds16(Ag + p * pstr, SMEM + t8 + p * 2048);
#pragma unroll
  for (int p = 0; p < 4; ++p) glds16(Bg + p * pstr, SMEM + 8192 + t8 + p * 2048);

  for (int i = 0; i < niter; ++i) {
    const int c = i & 1;
    if (i + 1 < niter) {
      const int k1 = (i + 1) << 6;
      short* dst = SMEM + (1 - c) * 16384 + t8;
#pragma unroll
      for (int p = 0; p < 4; ++p) glds16(Ag + k1 + p * pstr, dst + p * 2048);
#pragma unroll
      for (int p = 0; p < 4; ++p) glds16(Bg + k1 + p * pstr, dst + 8192 + p * 2048);
      WAITV(8);
    } else {
      WAITV(0);
    }
    SBAR();

    const short* As = SMEM + c * 16384;
    const short* Bs = As + 8192;
#pragma unroll
    for (int kk = 0; kk < 2; ++kk) {
      s8v af[4], bf[4];
#pragma unroll
      for (int ii = 0; ii < 4; ++ii)
        af[ii] = *(const s8v*)&As[(wm + ii * 16 + l16) * 64 + (((kk * 4 + quad) ^ swq) * 8)];
#pragma unroll
      for (int j = 0; j < 4; ++j)
        bf[j] = *(const s8v*)&Bs[(wn + j * 16 + l16) * 64 + (((kk * 4 + quad) ^ swq) * 8)];
#pragma unroll
      for (int ii = 0; ii < 4; ++ii)
#pragma unroll
        for (int j = 0; j < 4; ++j)
          acc[ii][j] = __builtin_amdgcn_mfma_f32_16x16x32_bf16(af[ii], bf[j], acc[ii][j], 0, 0, 0);
    }
    SBAR();
  }

  // ---- epilogue ----
  float bv[4];
  if (EPI == EPI_BIAS || EPI == EPI_BIAS_T) {
#pragma unroll
    for (int j = 0; j < 4; ++j) bv[j] = bias[n0 + wn + j * 16 + l16];
  }

  if (EPI == EPI_BIAS_T) {
#pragma unroll
    for (int i = 0; i < 4; ++i) {
#pragma unroll
      for (int j = 0; j < 4; ++j) {
        const int gn  = n0 + wn + j * 16 + l16;
        const int gmb = m0 + wm + i * 16 + quad * 4;
        const int bb = gmb >> 11, ssb = gmb & (S_LEN - 1);
        s4v o;
#pragma unroll
        for (int r = 0; r < 4; ++r) o[r] = f2bf_s(acc[i][j][r] + bv[j]);
        *(s4v*)&C[((size_t)bb * D_DIM + gn) * S_LEN + ssb] = o;
      }
    }
    return;
  }

  // EPI_BIAS / EPI_SCORES: LDS transpose -> coalesced 16B row stores.
  short* TB = SMEM;                 // 4 waves x 2176 shorts (32 rows x stride 68)
  const int wbase = w * 2176;
  float csum[4] = {0.f, 0.f, 0.f, 0.f};

#pragma unroll
  for (int ph = 0; ph < 2; ++ph) {
    __syncthreads();
#pragma unroll
    for (int ii = 0; ii < 2; ++ii) {
      const int i = ph * 2 + ii;
#pragma unroll
      for (int j = 0; j < 4; ++j) {
        const int gn = n0 + wn + j * 16 + l16;
#pragma unroll
        for (int r = 0; r < 4; ++r) {
          short o;
          if (EPI == EPI_SCORES) {
            const int gm = m0 + wm + i * 16 + quad * 4 + r;
            const float f = (gm >= gn) ? (__expf(acc[i][j][r] * SCALE_F) - 1.0f) : 0.0f;
            csum[j] += f;
            o = f2bf_s(f);
          } else {
            o = f2bf_s(acc[i][j][r] + bv[j]);
          }
          TB[wbase + (ii * 16 + quad * 4 + r) * 68 + j * 16 + l16] = o;
        }
      }
    }
    __syncthreads();
#pragma unroll
    for (int p = 0; p < 4; ++p) {
      const int row = p * 8 + (lane >> 3);   // 0..31
      const int cg  = lane & 7;
      const s8v vv = *(const s8v*)&TB[wbase + row * 68 + cg * 8];
      const int gm = m0 + wm + ph * 32 + row;
      const int gn = n0 + wn + cg * 8;
      *(s8v*)&C[sCz + (size_t)gm * N + gn] = vv;
    }
  }

  if (EPI == EPI_SCORES) {
    // per-block partial column sums -> ZP[bz][m0>>7][n0..n0+128), non-atomic.
    float* LZ = (float*)(SMEM + 16384);   // 256 floats, beyond TB region
#pragma unroll
    for (int j = 0; j < 4; ++j) {
      float cs = csum[j];
      cs += __shfl_xor(cs, 16, 64);
      cs += __shfl_xor(cs, 32, 64);
      if (quad == 0) LZ[(w >> 1) * 128 + wn + j * 16 + l16] = cs;
    }
    __syncthreads();
    if (tid < 128)
      ZP[(((bz << 4) + (m0 >> 7)) << 11) + n0 + tid] = LZ[tid] + LZ[128 + tid];
  }
}

// scores-F kernel: 128x128 tiles, compact triangular grid x in [0,136), z=batch.
__global__ __launch_bounds__(256, 2) void gemm_scoresF(
    const short* __restrict__ A, const short* __restrict__ B, short* __restrict__ C,
    float* __restrict__ ZP)
{
  __shared__ __align__(16) short SMEM[32768];   // 64 KB
  const int bz = blockIdx.z;
  const int t = blockIdx.x;
  int ti = (int)((sqrtf(8.0f * t + 1.0f) - 1.0f) * 0.5f);
  while ((ti + 1) * (ti + 2) / 2 <= t) ++ti;
  while (ti * (ti + 1) / 2 > t) --ti;
  const int tj = t - ti * (ti + 1) / 2;         // tj <= ti
  gemm_core<EPI_SCORES>(A + (size_t)bz * S_LEN * D_DIM, B + (size_t)bz * S_LEN * D_DIM,
                        C, nullptr, SMEM, S_LEN, D_DIM,
                        (size_t)bz * S_LEN * S_LEN, ti * 128, tj * 128, bz, ZP);
}

// three projections: 128x128 tiles, z=0 -> qp, z=1 -> kp, z=2 -> vpT (transposed)
__global__ __launch_bounds__(256, 2) void proj3(
    const short* __restrict__ a0, const short* __restrict__ a1, const short* __restrict__ a2,
    const short* __restrict__ b0, const short* __restrict__ b1, const short* __restrict__ b2,
    short* __restrict__ c0, short* __restrict__ c1, short* __restrict__ c2,
    const float* __restrict__ x0, const float* __restrict__ x1, const float* __restrict__ x2)
{
  __shared__ __align__(16) short SMEM[32768];
  const int z = blockIdx.z;
  const short* A = (z == 0) ? a0 : (z == 1) ? a1 : a2;
  const short* B = (z == 0) ? b0 : (z == 1) ? b1 : b2;
  short*       C = (z == 0) ? c0 : (z == 1) ? c1 : c2;
  const float* bias = (z == 0) ? x0 : (z == 1) ? x1 : x2;
  if (z == 2)
    gemm_core<EPI_BIAS_T>(A, B, C, bias, SMEM, D_DIM, D_DIM, 0,
                          blockIdx.y * 128, blockIdx.x * 128, 0, nullptr);
  else
    gemm_core<EPI_BIAS>(A, B, C, bias, SMEM, D_DIM, D_DIM, 0,
                        blockIdx.y * 128, blockIdx.x * 128, 0, nullptr);
}

// out = F @ vpT'^T + T, 64x128 tiles, K truncated at m0+64, triple-buffered.
// SMEM: buf c at c*12288; As=+0 (64x64), Bs=+4096 (128x64).
__global__ __launch_bounds__(256, 2) void gemm_outF(
    const short* __restrict__ F, const short* __restrict__ vpT,
    const float* __restrict__ Tv, float* __restrict__ out)
{
  __shared__ __align__(16) short SMEM[36864];   // 72 KB

  const int tid  = threadIdx.x;
  const int bz   = blockIdx.z;
  const int m0   = (31 - blockIdx.y) * 64;      // longest blocks dispatch first
  const int n0   = blockIdx.x * 128;

  const short* A = F   + (size_t)bz * S_LEN * S_LEN;
  const short* B = vpT + (size_t)bz * D_DIM * S_LEN;

  const int w    = tid >> 6;
  const int lane = tid & 63;
  const int quad = lane >> 4;
  const int l16  = lane & 15;
  const int wm   = (w >> 1) * 32;
  const int wn   = (w & 1) * 64;

  const int strow = tid >> 3;
  const int gl = ((tid & 7) ^ (strow & 7)) * 8;

  f4v acc[2][4];
#pragma unroll
  for (int i = 0; i < 2; ++i)
#pragma unroll
    for (int j = 0; j < 4; ++j)
#pragma unroll
      for (int r = 0; r < 4; ++r) acc[i][j][r] = 0.0f;

  const short* Ag = A + (size_t)(m0 + strow) * S_LEN + gl;
  const short* Bg = B + (size_t)(n0 + strow) * S_LEN + gl;
  const size_t pstr = (size_t)32 * S_LEN;
  const int t8 = tid * 8;
  const int swq = l16 & 7;

  const int niter = (m0 >> 6) + 1;   // K runs 0 .. m0+64

#pragma unroll
  for (int pre = 0; pre < 2; ++pre) {
    short* dst = SMEM + pre * 12288 + t8;
    const int k0 = pre << 6;
#pragma unroll
    for (int p = 0; p < 2; ++p) glds16(Ag + k0 + p * pstr, dst + p * 2048);
#pragma unroll
    for (int p = 0; p < 4; ++p) glds16(Bg + k0 + p * pstr, dst + 4096 + p * 2048);
  }

  int cbuf = 0, nbuf = 2;
  for (int i = 0; i < niter; ++i) {
    if (i + 2 < niter) {
      const int k2 = (i + 2) << 6;
      short* dst = SMEM + nbuf * 12288 + t8;
#pragma unroll
      for (int p = 0; p < 2; ++p) glds16(Ag + k2 + p * pstr, dst + p * 2048);
#pragma unroll
      for (int p = 0; p < 4; ++p) glds16(Bg + k2 + p * pstr, dst + 4096 + p * 2048);
      nbuf = (nbuf == 2) ? 0 : nbuf + 1;
      WAITV(12);
    } else if (i + 1 < niter) {
      WAITV(6);
    } else {
      WAITV(0);
    }
    SBAR();

    const short* As = SMEM + cbuf * 12288;
    const short* Bs = As + 4096;
    cbuf = (cbuf == 2) ? 0 : cbuf + 1;
#pragma unroll
    for (int kk = 0; kk < 2; ++kk) {
      s8v af[2], bf[4];
#pragma unroll
      for (int ii = 0; ii < 2; ++ii)
        af[ii] = *(const s8v*)&As[(wm + ii * 16 + l16) * 64 + (((kk * 4 + quad) ^ swq) * 8)];
#pragma unroll
      for (int j = 0; j < 4; ++j)
        bf[j] = *(const s8v*)&Bs[(wn + j * 16 + l16) * 64 + (((kk * 4 + quad) ^ swq) * 8)];
#pragma unroll
      for (int ii = 0; ii < 2; ++ii)
#pragma unroll
        for (int j = 0; j < 4; ++j)
          acc[ii][j] = __builtin_amdgcn_mfma_f32_16x16x32_bf16(af[ii], bf[j], acc[ii][j], 0, 0, 0);
    }
    SBAR();
  }

  float* Cf = out + (size_t)bz * S_LEN * D_DIM;
#pragma unroll
  for (int i = 0; i < 2; ++i) {
#pragma unroll
    for (int j = 0; j < 4; ++j) {
      const int gn = n0 + wn + j * 16 + l16;
      const float tvn = Tv[(bz << 9) + gn];
#pragma unroll
      for (int r = 0; r < 4; ++r) {
        const int gm = m0 + wm + i * 16 + quad * 4 + r;
        Cf[(size_t)gm * D_DIM + gn] = acc[i][j][r] + tvn;
      }
    }
  }
}

// one launch for all fp32->bf16 conversions: x<2048 -> q/k/v slab y, else weights y
__global__ __launch_bounds__(256) void cvt6(
    const float* __restrict__ q, const float* __restrict__ k, const float* __restrict__ v,
    const float* __restrict__ wq, const float* __restrict__ wk, const float* __restrict__ wv,
    short* __restrict__ dstBig, short* __restrict__ dstW)
{
  const int y = blockIdx.y;
  const float* s;
  short* d;
  int i;
  if (blockIdx.x < 2048) {
    s = (y == 0) ? q : (y == 1) ? k : v;
    d = dstBig + (size_t)y * 4194304;
    i = (blockIdx.x * 256 + threadIdx.x) * 8;
  } else {
    s = (y == 0) ? wq : (y == 1) ? wk : wv;
    d = dstW + (size_t)y * 262144;
    i = ((blockIdx.x - 2048) * 256 + threadIdx.x) * 8;
  }
  const float4 f0 = *(const float4*)(s + i);
  const float4 f1 = *(const float4*)(s + i + 4);
  s8v o;
  o[0] = f2bf_s(f0.x); o[1] = f2bf_s(f0.y); o[2] = f2bf_s(f0.z); o[3] = f2bf_s(f0.w);
  o[4] = f2bf_s(f1.x); o[5] = f2bf_s(f1.y); o[6] = f2bf_s(f1.z); o[7] = f2bf_s(f1.w);
  *(s8v*)(d + i) = o;
}

// rsZ[b][k] = 1/(2048 + sum_{i=(k>>7)}^{15} ZP[b][i][k])
__global__ __launch_bounds__(256) void zfin(
    const float* __restrict__ ZP, float* __restrict__ rsZ)
{
  const int idx = blockIdx.x * 256 + threadIdx.x;   // < 8192
  const int b = idx >> 11, kk = idx & (S_LEN - 1);
  float s = 2048.0f;
  for (int i = (kk >> 7); i < 16; ++i)
    s += ZP[(((b << 4) + i) << 11) + kk];
  rsZ[idx] = 1.0f / s;
}

// block per (b,d): vpT[b][d][k] *= rsZ[b][k]; Tv[b,d] = sum_k (fp32)
__global__ __launch_bounds__(256) void scale_vpt_T(
    short* __restrict__ vpT, const float* __restrict__ rsZ, float* __restrict__ Tv)
{
  __shared__ float red[4];
  const int b = blockIdx.y, d = blockIdx.x, tid = threadIdx.x;
  const size_t rowbase = ((size_t)(b * D_DIM + d)) * S_LEN;
  const float* rz = rsZ + (b << 11);
  const int k0 = tid * 8;

  const float4 z0 = *(const float4*)&rz[k0];
  const float4 z1 = *(const float4*)&rz[k0 + 4];
  s8v v = *(s8v*)&vpT[rowbase + k0];
  float wv0 = bf2f_s(v[0]) * z0.x, wv1 = bf2f_s(v[1]) * z0.y;
  float wv2 = bf2f_s(v[2]) * z0.z, wv3 = bf2f_s(v[3]) * z0.w;
  float wv4 = bf2f_s(v[4]) * z1.x, wv5 = bf2f_s(v[5]) * z1.y;
  float wv6 = bf2f_s(v[6]) * z1.z, wv7 = bf2f_s(v[7]) * z1.w;
  float s = ((wv0 + wv1) + (wv2 + wv3)) + ((wv4 + wv5) + (wv6 + wv7));
  v[0] = f2bf_s(wv0); v[1] = f2bf_s(wv1); v[2] = f2bf_s(wv2); v[3] = f2bf_s(wv3);
  v[4] = f2bf_s(wv4); v[5] = f2bf_s(wv5); v[6] = f2bf_s(wv6); v[7] = f2bf_s(wv7);
  *(s8v*)&vpT[rowbase + k0] = v;

#pragma unroll
  for (int off = 32; off >= 1; off >>= 1) s += __shfl_xor(s, off, 64);
  if ((tid & 63) == 0) red[tid >> 6] = s;
  __syncthreads();
  if (tid == 0) Tv[(b << 9) + d] = red[0] + red[1] + red[2] + red[3];
}

extern "C" void kernel_launch(void* const* d_in, const int* in_sizes, int n_in,
                              void* d_out, int out_size, void* d_ws, size_t ws_size,
                              hipStream_t stream) {
  const float* q   = (const float*)d_in[0];
  const float* k   = (const float*)d_in[1];
  const float* v   = (const float*)d_in[2];
  const float* WQw = (const float*)d_in[3];
  const float* WQb = (const float*)d_in[4];
  const float* WKw = (const float*)d_in[5];
  const float* WKb = (const float*)d_in[6];
  const float* WVw = (const float*)d_in[7];
  const float* WVb = (const float*)d_in[8];

  char* ws = (char*)d_ws;
  // F occupies [0,32M); bf16 input/weight copies alias its head (dead before F written)
  short* F   = (short*)(ws);                 // 32 MB  [4][2048][2048] (lower tiles only)
  short* qb  = (short*)(ws);                 //  8 MB  (qb,kb,vb contiguous)
  short* Wqb = (short*)(ws + 25165824);      // 3x 512 KB contiguous
  short* qp  = (short*)(ws + 33554432);      //  8 MB  [4][2048][512]
  short* kp  = (short*)(ws + 41943040);      //  8 MB
  short* vpT = (short*)(ws + 50331648);      //  8 MB  [4][512][2048]
  float* ZP  = (float*)(ws + 58720256);      // 512 KB [4][16][2048] partial colsums
  float* rsZ = (float*)(ws + 59244544);      // 32 KB  [4][2048]
  float* Tv  = (float*)(ws + 59277312);      //  8 KB  [4][512]
  short* kb  = qb + 4194304;
  short* vb  = qb + 8388608;
  short* Wkb = Wqb + 262144;
  short* Wvb = Wqb + 524288;

  const dim3 blk(256);

  // all fp32 -> bf16 conversions, one launch
  cvt6<<<dim3(2176, 3), blk, 0, stream>>>(q, k, v, WQw, WKw, WVw, qb, Wqb);

  // projections: M=8192, N=512, K=512; 128x128 tiles -> 768 blocks
  proj3<<<dim3(4, 64, 3), blk, 0, stream>>>(
      qb, kb, vb, Wqb, Wkb, Wvb, qp, kp, vpT, WQb, WKb, WVb);

  // F = expm1(scale*qp@kp^T) lower-tri 128x128 tiles + ZP partial colsums
  gemm_scoresF<<<dim3(136, 1, 4), blk, 0, stream>>>(qp, kp, F, ZP);

  // rsZ = 1/(2048 + colsum)
  zfin<<<dim3(32), blk, 0, stream>>>(ZP, rsZ);

  // vpT' = vpT * rsZ; Tv = rowsum(vpT')
  scale_vpt_T<<<dim3(512, 4), blk, 0, stream>>>(vpT, rsZ, Tv);

  // out = F @ vpT'^T + Tv: 64x128 tiles, K truncated at m0+64
  gemm_outF<<<dim3(4, 32, 4), blk, 0, stream>>>(F, vpT, Tv, (float*)d_out);
}